// Round 2
// baseline (374.578 us; speedup 1.0000x reference)
//
// VQ layer (gumbel-softmax VQ) fused pipeline for MI355X (gfx950).
//
// Decomposition:
//   K0a split_w : W_h, W_logits (512x512 f32) -> f16 hi/lo planes in ws (2 MB)
//   K0b split_x : X (65536x512 f32) -> f16 hi/lo planes in ws (if ws fits)
//   K1  gemm    : hiddens = relu(X @ Wh^T + bh)  -> f16 hi/lo planes stored in
//                 the *codes* half of d_out (134 MB, free real estate until K3)
//   K2  gemm    : logits = hiddens @ Wl^T + bl -> d_out[0 : 33.5M] (f32)
//   K3  argmax  : z = logits + gumbel(u); codes[row,:] = codebook[argmax z,:]
//
// f32-GEMM emulation: a = hi + lo (f16 split, lo scaled by 2^12 to stay out of
// f16 denormal range), D = (hi.hi) + (hi.lo' + lo'.hi) * 2^-12, f32 MFMA accum.
// Per-term rel error ~2^-23 -> logits match reference to ~1e-7 (same order as
// accumulation-order differences).

#include <hip/hip_runtime.h>
#include <hip/hip_fp16.h>

typedef _Float16 h16;
typedef __attribute__((ext_vector_type(8))) _Float16 h16x8;
typedef __attribute__((ext_vector_type(4))) _Float16 h16x4;
typedef __attribute__((ext_vector_type(4))) float f32x4;

#define M_TOTAL 65536
#define KDIM 512
#define NDIM 512
#define BM 128
#define BN 128
#define BK 64
#define LO_SCALE 4096.0f
#define LO_INV   0.000244140625f

__device__ __forceinline__ void gload16(const void* g, void* l) {
  __builtin_amdgcn_global_load_lds((const __attribute__((address_space(1))) void*)g,
                                   (__attribute__((address_space(3))) void*)l, 16, 0, 0);
}

// ---------------- K0a: split weights into f16 hi/lo planes ----------------
__global__ void split_w(const float* __restrict__ Wh, const float* __restrict__ Wl,
                        h16* __restrict__ WhHi, h16* __restrict__ WhLo,
                        h16* __restrict__ WlHi, h16* __restrict__ WlLo) {
  int i = blockIdx.x * 256 + threadIdx.x;          // 262144 elements
  float a = Wh[i];
  h16 h = (h16)a;
  WhHi[i] = h; WhLo[i] = (h16)((a - (float)h) * LO_SCALE);
  a = Wl[i];
  h = (h16)a;
  WlHi[i] = h; WlLo[i] = (h16)((a - (float)h) * LO_SCALE);
}

// ---------------- K0b: split inputs into f16 hi/lo planes ----------------
__global__ void split_x(const f32x4* __restrict__ X, h16x4* __restrict__ XHi,
                        h16x4* __restrict__ XLo) {
  int i = blockIdx.x * 256 + threadIdx.x;          // 8388608 f32x4 groups
  f32x4 a = X[i];
  h16x4 hv, lv;
#pragma unroll
  for (int j = 0; j < 4; ++j) {
    h16 h = (h16)a[j];
    hv[j] = h;
    lv[j] = (h16)((a[j] - (float)h) * LO_SCALE);
  }
  XHi[i] = hv; XLo[i] = lv;
}

// ---------------- GEMM: C[m,n] = sum_k A[m,k]*B[n,k] (+bias, epilogue) ----
// APRE: A is pre-split f16 planes; else A is f32, split on the fly.
// EPI 0: relu + split -> OHi/OLo planes.  EPI 1: f32 store to Cf32.
template <bool APRE, int EPI>
__launch_bounds__(256, 2)
__global__ void gemm_k(const void* __restrict__ Aptr, const void* __restrict__ AptrLo,
                       const h16* __restrict__ BHi, const h16* __restrict__ BLo,
                       const float* __restrict__ bias,
                       float* __restrict__ Cf32,
                       h16* __restrict__ OHi, h16* __restrict__ OLo) {
  // LDS layout (64 KB):
  //  APRE : [0,16K) A_hi [16K,32K) A_lo [32K,48K) B_hi [48K,64K) B_lo
  //  !APRE: [0,32K) A_f32            [32K,48K) B_hi [48K,64K) B_lo
  __shared__ __align__(16) char lds[65536];
  const int tid = threadIdx.x;
  const int wave = tid >> 6, lane = tid & 63;
  const int bm = blockIdx.x >> 2;                  // 512 row-tiles
  const int bn = blockIdx.x & 3;                   // 4 col-tiles
  const int wm = wave >> 1, wn = wave & 1;         // 2x2 wave grid, 64x64/wave

  const long arow0 = (long)bm * BM;
  const int brow0 = bn * BN;
  const char* Abase = (const char*)Aptr;
  const char* AbaseLo = (const char*)AptrLo;

  f32x4 acc_hh[4][4] = {};
  f32x4 acc_mx[4][4] = {};

  for (int kt = 0; kt < KDIM / BK; ++kt) {
    const int kb = kt * BK;
    // ---- stage tiles (global_load_lds, 16B/lane, XOR-swizzled source) ----
    if (APRE) {
#pragma unroll
      for (int pass = 0; pass < 4; ++pass) {
        int wb = pass * 4096 + wave * 1024;
        int p = wb + lane * 16;
        int row = p >> 7;                          // 128B rows ([128][64] f16)
        int q = p ^ ((row & 7) << 4);
        long off = ((arow0 + row) * KDIM + kb) * 2 + (q & 127);
        gload16(Abase + off, lds + wb);
        gload16(AbaseLo + off, lds + 16384 + wb);
      }
    } else {
#pragma unroll
      for (int pass = 0; pass < 8; ++pass) {
        int wb = pass * 4096 + wave * 1024;
        int p = wb + lane * 16;
        int row = p >> 8;                          // 256B rows ([128][64] f32)
        int q = p ^ ((row & 15) << 4);
        long off = ((arow0 + row) * KDIM + kb) * 4 + (q & 255);
        gload16(Abase + off, lds + wb);
      }
    }
#pragma unroll
    for (int pass = 0; pass < 4; ++pass) {
      int wb = pass * 4096 + wave * 1024;
      int p = wb + lane * 16;
      int row = p >> 7;
      int q = p ^ ((row & 7) << 4);
      long off = ((long)(brow0 + row) * KDIM + kb) * 2 + (q & 127);
      gload16((const char*)BHi + off, lds + 32768 + wb);
      gload16((const char*)BLo + off, lds + 49152 + wb);
    }
    __syncthreads();

    // ---- compute ----
#pragma unroll
    for (int ks = 0; ks < 2; ++ks) {
      const int k0 = ks * 32 + (lane >> 4) * 8;    // 8 contiguous k per lane
      h16x8 ah[4], al[4], bh[4], bl[4];
#pragma unroll
      for (int i = 0; i < 4; ++i) {
        int row = wm * 64 + i * 16 + (lane & 15);
        if (APRE) {
          int byt = (row * 128 + k0 * 2) ^ ((row & 7) << 4);
          ah[i] = *(const h16x8*)(lds + byt);
          al[i] = *(const h16x8*)(lds + 16384 + byt);
        } else {
          int b0 = (row * 256 + k0 * 4) ^ ((row & 15) << 4);
          int b1 = (row * 256 + k0 * 4 + 16) ^ ((row & 15) << 4);
          f32x4 u0 = *(const f32x4*)(lds + b0);
          f32x4 u1 = *(const f32x4*)(lds + b1);
#pragma unroll
          for (int t = 0; t < 4; ++t) {
            h16 h = (h16)u0[t];
            ah[i][t] = h; al[i][t] = (h16)((u0[t] - (float)h) * LO_SCALE);
          }
#pragma unroll
          for (int t = 0; t < 4; ++t) {
            h16 h = (h16)u1[t];
            ah[i][4 + t] = h; al[i][4 + t] = (h16)((u1[t] - (float)h) * LO_SCALE);
          }
        }
      }
#pragma unroll
      for (int j = 0; j < 4; ++j) {
        int row = wn * 64 + j * 16 + (lane & 15);
        int byt = (row * 128 + k0 * 2) ^ ((row & 7) << 4);
        bh[j] = *(const h16x8*)(lds + 32768 + byt);
        bl[j] = *(const h16x8*)(lds + 49152 + byt);
      }
#pragma unroll
      for (int i = 0; i < 4; ++i)
#pragma unroll
        for (int j = 0; j < 4; ++j) {
          acc_hh[i][j] = __builtin_amdgcn_mfma_f32_16x16x32_f16(ah[i], bh[j], acc_hh[i][j], 0, 0, 0);
          acc_mx[i][j] = __builtin_amdgcn_mfma_f32_16x16x32_f16(ah[i], bl[j], acc_mx[i][j], 0, 0, 0);
          acc_mx[i][j] = __builtin_amdgcn_mfma_f32_16x16x32_f16(al[i], bh[j], acc_mx[i][j], 0, 0, 0);
        }
    }
    __syncthreads();
  }

  // ---- epilogue: C/D layout col=lane&15, row=(lane>>4)*4+r (m89-verified) --
#pragma unroll
  for (int j = 0; j < 4; ++j) {
    int col = bn * BN + wn * 64 + j * 16 + (lane & 15);
    float bv = bias[col];
#pragma unroll
    for (int i = 0; i < 4; ++i) {
      long row = (long)bm * BM + wm * 64 + i * 16 + ((lane >> 4) * 4);
#pragma unroll
      for (int r = 0; r < 4; ++r) {
        float v = acc_hh[i][j][r] + acc_mx[i][j][r] * LO_INV + bv;
        long idx = (row + r) * (long)NDIM + col;
        if (EPI == 0) {
          v = fmaxf(v, 0.0f);
          h16 h = (h16)v;
          OHi[idx] = h;
          OLo[idx] = (h16)((v - (float)h) * LO_SCALE);
        } else {
          Cf32[idx] = v;
        }
      }
    }
  }
}

// ---------------- K3: gumbel + argmax + codebook gather ----------------
__global__ void k3_argmax_gather(const float* __restrict__ logits,
                                 const float* __restrict__ u,
                                 const float* __restrict__ cb,
                                 const int* __restrict__ testing,
                                 float* __restrict__ codes) {
  const int wave = threadIdx.x >> 6, lane = threadIdx.x & 63;
  const long row = (long)blockIdx.x * 4 + wave;    // one wave per row
  const float* lrow = logits + row * 512;
  const float* urow = u + row * 512;
  const int test = *testing;

  float best = -3.4e38f;
  int bi = 0;
  for (int c0 = 0; c0 < 512; c0 += 64) {           // ascending -> first-max tie
    int c = c0 + lane;
    float z = lrow[c];
    if (!test) {
      float uu = urow[c] + 1e-20f;
      float g = -logf(-logf(uu) + 1e-20f);         // matches ref formula in f32
      z += g;
    }
    if (z > best) { best = z; bi = c; }
  }
#pragma unroll
  for (int off = 32; off; off >>= 1) {             // max with min-index ties
    float ob = __shfl_xor(best, off);
    int oi = __shfl_xor(bi, off);
    if (ob > best || (ob == best && oi < bi)) { best = ob; bi = oi; }
  }
  const f32x4* src = (const f32x4*)(cb + (long)bi * 512);
  f32x4* dst = (f32x4*)(codes + row * 512);
  dst[lane] = src[lane];
  dst[lane + 64] = src[lane + 64];
}

// ---------------- host ----------------
extern "C" void kernel_launch(void* const* d_in, const int* in_sizes, int n_in,
                              void* d_out, int out_size, void* d_ws, size_t ws_size,
                              hipStream_t stream) {
  const float* X = (const float*)d_in[0];
  const float* Wh = (const float*)d_in[1];
  const float* bh = (const float*)d_in[2];
  const float* Wl = (const float*)d_in[3];
  const float* bl = (const float*)d_in[4];
  const float* cb = (const float*)d_in[5];
  const float* u = (const float*)d_in[6];
  const int* testing = (const int*)d_in[7];

  float* logits = (float*)d_out;                   // 33554432 f32
  float* codes = logits + 33554432;                // 33554432 f32
  // hiddens hi/lo f16 planes live in the codes region until K3 overwrites it
  h16* Hhi = (h16*)codes;
  h16* Hlo = Hhi + 33554432;

  h16* WhHi = (h16*)d_ws;                          // 4 x 0.5 MB weight planes
  h16* WhLo = WhHi + 262144;
  h16* WlHi = WhLo + 262144;
  h16* WlLo = WlHi + 262144;
  h16* Xhi = (h16*)((char*)d_ws + 2097152);        // optional 134 MB X planes
  h16* Xlo = Xhi + 33554432;
  const bool presplit = ws_size >= (size_t)2097152 + (size_t)134217728;

  split_w<<<dim3(1024), dim3(256), 0, stream>>>(Wh, Wl, WhHi, WhLo, WlHi, WlLo);

  if (presplit) {
    split_x<<<dim3(32768), dim3(256), 0, stream>>>((const f32x4*)X, (h16x4*)Xhi, (h16x4*)Xlo);
    gemm_k<true, 0><<<dim3(2048), dim3(256), 0, stream>>>(
        (const void*)Xhi, (const void*)Xlo, WhHi, WhLo, bh, nullptr, Hhi, Hlo);
  } else {
    gemm_k<false, 0><<<dim3(2048), dim3(256), 0, stream>>>(
        (const void*)X, nullptr, WhHi, WhLo, bh, nullptr, Hhi, Hlo);
  }
  gemm_k<true, 1><<<dim3(2048), dim3(256), 0, stream>>>(
      (const void*)Hhi, (const void*)Hlo, WlHi, WlLo, bl, logits, nullptr, nullptr);

  k3_argmax_gather<<<dim3(16384), dim3(256), 0, stream>>>(logits, u, cb, testing, codes);
}